// Round 5
// baseline (200.975 us; speedup 1.0000x reference)
//
#include <hip/hip_runtime.h>
#include <math.h>

#define N_SETS 4096
#define WAVES 8
#define SPW 2                               // sets per wave
#define SETS_PER_BLOCK (WAVES * SPW)        // 16
#define GRID_MAIN (N_SETS / SETS_PER_BLOCK) // 256 blocks = 1 per CU

typedef _Float16 f16;
typedef __attribute__((ext_vector_type(8))) _Float16 f16x8;
typedef __attribute__((ext_vector_type(4))) _Float16 f16x4;
typedef __attribute__((ext_vector_type(4))) float     f32x4;

template <int V> struct IC { static constexpr int value = V; };

// ---------------- ws layout ----------------
#define WS_PE    0         // fp32 [64][256]  65536
#define WS_QH    65536     // f16  [64][32]   4096
#define WS_WKV   69632     // f16  [64][256]  32768  (rows 0-31 Wk, 32-63 Wv)
#define WS_WMAPH 102400    // f16  [256][32]  16384
#define WS_PEH   118784    // f16  [64][256]  32768
#define WS_PTR   151552    // int  [4097]

// aux1: blocks [0,768) -> batch_ptr + out2 echo; blocks [768,832) -> pe table
__global__ void k_aux1(const int* __restrict__ batch, float* __restrict__ out2,
                       int* __restrict__ ptr, int N, float* __restrict__ pe) {
    int blk = blockIdx.x;
    if (blk < 768) {
        int i = blk * 256 + threadIdx.x;
        if (i >= N) return;
        int b = batch[i];
        out2[i] = (float)b;
        if (i == 0 || batch[i - 1] != b) ptr[b] = i;
        if (i == N - 1) ptr[N_SETS] = N;
    } else {
        int idx = (blk - 768) * 256 + threadIdx.x;   // 0..16383
        int p = idx >> 8, i = idx & 255;
        float e   = (float)(2 * (i / 2)) / 256.0f;
        float inv = powf(10000.0f, -e);
        float ang = (float)p * inv;
        pe[idx] = (i & 1) ? cosf(ang) : sinf(ang);
    }
}

// aux2: [0,96) weight f16 convert; [96,160) peh convert; [160,168) qh
__global__ void k_aux2(const float* __restrict__ Wk, const float* __restrict__ Wv,
                       const float* __restrict__ Wq, const float* __restrict__ Wmap,
                       const float* __restrict__ pe, f16* __restrict__ wkv,
                       f16* __restrict__ wmaph, f16* __restrict__ peh,
                       f16* __restrict__ qh) {
    int blk = blockIdx.x;
    if (blk < 96) {
        int idx = blk * 256 + threadIdx.x;           // 0..24575
        if (idx < 16384) {
            int j = idx >> 8, d = idx & 255;
            float v = (j < 32) ? Wk[j * 256 + d] : Wv[(j - 32) * 256 + d];
            wkv[idx] = (f16)v;
        } else {
            int i2 = idx - 16384;
            wmaph[i2] = (f16)Wmap[i2];
        }
    } else if (blk < 160) {
        int idx = (blk - 96) * 256 + threadIdx.x;    // 0..16383
        peh[idx] = (f16)pe[idx];
    } else {
        int idx = (blk - 160) * 256 + threadIdx.x;   // 0..2047
        int pos = idx >> 5, k = idx & 31;
        const float* pr = pe + pos * 256;
        const float* wr = Wq + k * 256;
        float s = 0.f;
        for (int d = 0; d < 256; d += 4) {
            float4 a = *(const float4*)(pr + d);
            float4 b = *(const float4*)(wr + d);
            s += a.x * b.x + a.y * b.y + a.z * b.z + a.w * b.w;
        }
        qh[idx] = (f16)s;
    }
}

// Per-wave independent set processing. 8 waves/block, 1 block/CU, grid = 256.
// Shared LDS (read-only after one barrier):
//   [0,     32768)  wsh f16 [64][256] swz ((j&7)<<4)   (Wk rows 0-31, Wv 32-63)
//   [32768, 49152)  wmh f16 [256][32] swz ((d&7)<<4)
//   [49152, 81920)  peh f16 [64][256] swz ((r&7)<<4)
// Per-wave scratch 8 KB @ 81920 + wid*8192:
//   phase1: YT f16 [64c][64r] swz ((c&7)<<4)          (8192 B)
//   phase2: zT f16 [32c][32r] swz ((c&3)<<4) @ +0     (2048 B, YT dead)
//           dsh f16 [64m][32v] swz ((m&7)<<4) @ +2048 (4096 B)
// No __syncthreads in the set loop: each wave touches only its own scratch;
// same-wave ds_write -> ds_read is ordered by the LDS pipeline.
__global__ __launch_bounds__(512, 2) void k_main(
        const float* __restrict__ x,     const f16* __restrict__ wkv,
        const f16* __restrict__ wmaph,   const f16* __restrict__ qh,
        const f16* __restrict__ peh,     const float* __restrict__ bmap,
        const int* __restrict__ ptr,     float* __restrict__ out) {
    __shared__ char lds[147456];

    const int t   = threadIdx.x;
    const int wid = t >> 6;
    const int l15 = t & 15;
    const int lhi = (t & 63) >> 4;        // 0..3
    char* wlds = lds + 81920 + (wid << 13);

    // ---- stage wsh ----
    #pragma unroll
    for (int i = 0; i < 4; ++i) {
        int c = t + 512 * i;
        int j = c >> 5, d0 = (c & 31) * 8;
        *(f16x8*)(lds + ((j * 512 + d0 * 2) ^ ((j & 7) << 4))) =
            *(const f16x8*)(wkv + j * 256 + d0);
    }
    // ---- stage wmh ----
    #pragma unroll
    for (int i = 0; i < 2; ++i) {
        int c = t + 512 * i;
        int d = c >> 2, v0 = (c & 3) * 8;
        *(f16x8*)(lds + 32768 + ((d * 64 + v0 * 2) ^ ((d & 7) << 4))) =
            *(const f16x8*)(wmaph + d * 32 + v0);
    }
    // ---- stage peh ----
    #pragma unroll
    for (int i = 0; i < 4; ++i) {
        int c = t + 512 * i;
        int j = c >> 5, d0 = (c & 31) * 8;
        *(f16x8*)(lds + 49152 + ((j * 512 + d0 * 2) ^ ((j & 7) << 4))) =
            *(const f16x8*)(peh + j * 256 + d0);
    }
    // ---- set-invariant registers ----
    f16x8 qregs[4];
    #pragma unroll
    for (int mt = 0; mt < 4; ++mt)
        qregs[mt] = *(const f16x8*)(qh + (16 * mt + l15) * 32 + lhi * 8);
    float bm[16];
    #pragma unroll
    for (int nt = 0; nt < 16; ++nt) bm[nt] = bmap[16 * nt + l15];
    __syncthreads();

    const int g0 = blockIdx.x * SETS_PER_BLOCK + wid * SPW;
    int s, n;

    auto process = [&](auto nmtc) {
        constexpr int NMT = decltype(nmtc)::value;
        const int swz7 = (l15 & 7) << 4;

        // ---- GEMM1: Y = (X+PE)*Wkv^T -> YT ----
        #pragma unroll
        for (int mt = 0; mt < NMT; ++mt) {
            const int arow = 16 * mt + l15;
            const bool act = arow < n;
            float4 raw[16];
            const float* xr = x + (size_t)(s + arow) * 256 + lhi * 8;
            if (act) {
                #pragma unroll
                for (int ks = 0; ks < 8; ++ks) {
                    raw[2 * ks]     = *(const float4*)(xr + ks * 32);
                    raw[2 * ks + 1] = *(const float4*)(xr + ks * 32 + 4);
                }
            }
            f16x8 areg[8];
            #pragma unroll
            for (int ks = 0; ks < 8; ++ks) {
                f16x8 h;
                if (act) {
                    float4 a = raw[2 * ks], a2 = raw[2 * ks + 1];
                    h[0]=(f16)a.x;  h[1]=(f16)a.y;  h[2]=(f16)a.z;  h[3]=(f16)a.w;
                    h[4]=(f16)a2.x; h[5]=(f16)a2.y; h[6]=(f16)a2.z; h[7]=(f16)a2.w;
                    f16x8 pef = *(const f16x8*)(lds + 49152 +
                        ((arow * 512 + (ks * 32 + lhi * 8) * 2) ^ swz7));
                    h = h + pef;
                } else {
                    #pragma unroll
                    for (int ii = 0; ii < 8; ++ii) h[ii] = (f16)0.f;
                }
                areg[ks] = h;
            }
            #pragma unroll
            for (int nt = 0; nt < 4; ++nt) {
                f32x4 acc = {0.f, 0.f, 0.f, 0.f};
                const int brow = 16 * nt + l15;
                #pragma unroll
                for (int ks = 0; ks < 8; ++ks) {
                    f16x8 bf = *(const f16x8*)(lds +
                        ((brow * 512 + ks * 64 + lhi * 16) ^ swz7));
                    acc = __builtin_amdgcn_mfma_f32_16x16x32_f16(areg[ks], bf, acc, 0, 0, 0);
                }
                const int col = 16 * nt + l15;
                const int row0 = 16 * mt + lhi * 4;
                f16x4 h4;
                #pragma unroll
                for (int q = 0; q < 4; ++q) h4[q] = (f16)acc[q];
                *(f16x4*)(wlds + ((col * 128 + row0 * 2) ^ swz7)) = h4;
            }
        }

        // ---- GEMM2: Z = YV^T * YK (all 4 tiles in regs, then store zT) ----
        f32x4 zt[4];
        #pragma unroll
        for (int ij = 0; ij < 4; ++ij) {
            const int it = ij >> 1, jt = ij & 1;
            f32x4 zacc = {0.f, 0.f, 0.f, 0.f};
            const int ca = 32 + 16 * it + l15, cb = 16 * jt + l15;
            #pragma unroll
            for (int ks = 0; ks < NMT / 2; ++ks) {
                const int r2 = ks * 64 + lhi * 16;
                f16x8 av = *(const f16x8*)(wlds + ((ca * 128 + r2) ^ swz7));
                f16x8 bk = *(const f16x8*)(wlds + ((cb * 128 + r2) ^ swz7));
                zacc = __builtin_amdgcn_mfma_f32_16x16x32_f16(av, bk, zacc, 0, 0, 0);
            }
            zt[ij] = zacc;
        }
        #pragma unroll
        for (int ij = 0; ij < 4; ++ij) {
            const int zc = 16 * (ij & 1) + l15, zr0 = 16 * (ij >> 1) + lhi * 4;
            f16x4 h4;
            #pragma unroll
            for (int q = 0; q < 4; ++q) h4[q] = (f16)zt[ij][q];
            *(f16x4*)(wlds + ((zc * 64 + zr0 * 2) ^ ((zc & 3) << 4))) = h4;
        }

        // ---- GEMM3: dec = query * Z -> dsh ----
        #pragma unroll
        for (int nt2 = 0; nt2 < 2; ++nt2) {
            const int zrow = 16 * nt2 + l15;
            f16x8 bz = *(const f16x8*)(wlds + ((zrow * 64 + lhi * 16) ^ ((zrow & 3) << 4)));
            #pragma unroll
            for (int mt = 0; mt < NMT; ++mt) {
                f32x4 dd = {0.f, 0.f, 0.f, 0.f};
                dd = __builtin_amdgcn_mfma_f32_16x16x32_f16(qregs[mt], bz, dd, 0, 0, 0);
                #pragma unroll
                for (int q = 0; q < 4; ++q) {
                    const int m = 16 * mt + lhi * 4 + q;
                    *(f16*)(wlds + 2048 + ((m * 64 + zrow * 2) ^ ((m & 7) << 4))) = (f16)dd[q];
                }
            }
        }

        // ---- GEMM4: out = dec * Wmap^T + bmap (bw hoisted over mt) ----
        f16x8 ad[NMT];
        #pragma unroll
        for (int mt = 0; mt < NMT; ++mt) {
            const int drow = 16 * mt + l15;
            ad[mt] = *(const f16x8*)(wlds + 2048 + ((drow * 64 + lhi * 16) ^ swz7));
        }
        float* ob = out + (size_t)s * 256;
        #pragma unroll
        for (int nt = 0; nt < 16; ++nt) {
            const int dcol = 16 * nt + l15;
            f16x8 bw = *(const f16x8*)(lds + 32768 + ((dcol * 64 + lhi * 16) ^ swz7));
            #pragma unroll
            for (int mt = 0; mt < NMT; ++mt) {
                f32x4 o = {0.f, 0.f, 0.f, 0.f};
                o = __builtin_amdgcn_mfma_f32_16x16x32_f16(ad[mt], bw, o, 0, 0, 0);
                const int row0 = 16 * mt + lhi * 4;
                #pragma unroll
                for (int q = 0; q < 4; ++q) {
                    const int row = row0 + q;
                    if (row < n) ob[(size_t)row * 256 + dcol] = o[q] + bm[nt];
                }
            }
        }
    };

    for (int sw = 0; sw < SPW; ++sw) {
        s = ptr[g0 + sw];
        n = ptr[g0 + sw + 1] - s;
        if (n > 32) process(IC<4>{});
        else        process(IC<2>{});
    }
}

extern "C" void kernel_launch(void* const* d_in, const int* in_sizes, int n_in,
                              void* d_out, int out_size, void* d_ws, size_t ws_size,
                              hipStream_t stream) {
    const float* x    = (const float*)d_in[0];
    const int*   batch= (const int*)  d_in[1];
    const float* Wk   = (const float*)d_in[2];
    const float* Wv   = (const float*)d_in[3];
    const float* Wq   = (const float*)d_in[4];
    const float* Wmap = (const float*)d_in[5];
    const float* bmap = (const float*)d_in[6];
    float* out = (float*)d_out;

    const int N = in_sizes[1];                 // 196608 rows
    float* pe    = (float*)((char*)d_ws + WS_PE);
    f16*   qh    = (f16*)  ((char*)d_ws + WS_QH);
    f16*   wkv   = (f16*)  ((char*)d_ws + WS_WKV);
    f16*   wmaph = (f16*)  ((char*)d_ws + WS_WMAPH);
    f16*   peh   = (f16*)  ((char*)d_ws + WS_PEH);
    int*   ptr   = (int*)  ((char*)d_ws + WS_PTR);
    float* out2  = out + (size_t)N * 256;      // output 1: batch echo as floats

    k_aux1<<<832, 256, 0, stream>>>(batch, out2, ptr, N, pe);
    k_aux2<<<168, 256, 0, stream>>>(Wk, Wv, Wq, Wmap, pe, wkv, wmaph, peh, qh);
    k_main<<<GRID_MAIN, 512, 0, stream>>>(x, wkv, wmaph, qh, peh, bmap, ptr, out);
}